// Round 1
// baseline (617.331 us; speedup 1.0000x reference)
//
#include <hip/hip_runtime.h>
#include <hip/hip_bf16.h>
#include <float.h>

#define LEAKY 0.2f
#define SCAN_B 512

// ---------------- CSR build ----------------
__global__ void deg_k(const int* __restrict__ dst, int* __restrict__ deg, int E) {
    int e = blockIdx.x * blockDim.x + threadIdx.x;
    if (e < E) atomicAdd(&deg[dst[e]], 1);
}

__global__ void scan1_k(const int* __restrict__ deg, int* __restrict__ offs,
                        int* __restrict__ bsum, int N) {
    __shared__ int s[SCAN_B];
    int i = blockIdx.x * SCAN_B + threadIdx.x;
    int v = (i < N) ? deg[i] : 0;
    s[threadIdx.x] = v;
    __syncthreads();
    for (int off = 1; off < SCAN_B; off <<= 1) {
        int t = (threadIdx.x >= off) ? s[threadIdx.x - off] : 0;
        __syncthreads();
        s[threadIdx.x] += t;
        __syncthreads();
    }
    if (i < N) offs[i] = s[threadIdx.x] - v;   // exclusive
    if (threadIdx.x == SCAN_B - 1) bsum[blockIdx.x] = s[threadIdx.x];
}

__global__ void scan2_k(int* __restrict__ bsum, int* __restrict__ offs, int NB, int N) {
    if (blockIdx.x == 0 && threadIdx.x == 0) {
        int run = 0;
        for (int b = 0; b < NB; b++) { int t = bsum[b]; bsum[b] = run; run += t; }
        offs[N] = run;
    }
}

__global__ void scan3_k(int* __restrict__ offs, const int* __restrict__ bsum, int N) {
    int i = blockIdx.x * blockDim.x + threadIdx.x;
    if (i < N) offs[i] += bsum[i / SCAN_B];
}

__global__ void scatter_k(const int* __restrict__ src, const int* __restrict__ dst,
                          const int* __restrict__ et, const int* __restrict__ offs,
                          int* __restrict__ cursor, int* __restrict__ ssrc,
                          int* __restrict__ setp, int E) {
    int e = blockIdx.x * blockDim.x + threadIdx.x;
    if (e < E) {
        int d = dst[e];
        int pos = atomicAdd(&cursor[d], 1);
        int j = offs[d] + pos;
        ssrc[j] = src[e];
        setp[j] = et[e];
    }
}

// ---------------- GAT layer kernels (H = 64 baked in) ----------------
template <int FIN>
__global__ __launch_bounds__(256) void gemm_k(const float* __restrict__ in,
                                              const float* __restrict__ W,
                                              float* __restrict__ h, int N) {
    __shared__ float Wl[FIN * 64];
    for (int t = threadIdx.x; t < FIN * 64; t += 256) Wl[t] = W[t];
    __syncthreads();
    int row = blockIdx.x * 4 + (threadIdx.x >> 6);
    int col = threadIdx.x & 63;
    if (row >= N) return;
    const float* ir = in + (size_t)row * FIN;
    float acc = 0.f;
#pragma unroll 8
    for (int k = 0; k < FIN; k++) acc += ir[k] * Wl[k * 64 + col];
    h[(size_t)row * 64 + col] = acc;
}

__global__ __launch_bounds__(256) void logits_k(const float* __restrict__ h,
                                                const float* __restrict__ a_s,
                                                const float* __restrict__ a_d,
                                                float* __restrict__ ls,
                                                float* __restrict__ ld_, int N) {
    int node = blockIdx.x * 4 + (threadIdx.x >> 6);
    int lane = threadIdx.x & 63;
    if (node >= N) return;
    float v = h[(size_t)node * 64 + lane];
    float ds = v * a_s[lane];
    float dd = v * a_d[lane];
    for (int o = 32; o > 0; o >>= 1) {
        ds += __shfl_xor(ds, o, 64);
        dd += __shfl_xor(dd, o, 64);
    }
    if (lane == 0) { ls[node] = ds; ld_[node] = dd; }
}

__global__ __launch_bounds__(256) void softmax_k(const int* __restrict__ offs,
                                                 const int* __restrict__ ssrc,
                                                 const int* __restrict__ setp,
                                                 const float* __restrict__ ls,
                                                 const float* __restrict__ ld_,
                                                 const float* __restrict__ etb,
                                                 float* __restrict__ ew,
                                                 float* __restrict__ denom, int N) {
    int n = blockIdx.x * blockDim.x + threadIdx.x;
    if (n >= N) return;
    int s0 = offs[n], s1 = offs[n + 1];
    float myld = ld_[n];
    float mx = -FLT_MAX;
    for (int j = s0; j < s1; j++) {
        float ev = ls[ssrc[j]] + myld + etb[setp[j]];
        ev = ev > 0.f ? ev : LEAKY * ev;
        ew[j] = ev;
        mx = fmaxf(mx, ev);
    }
    float s = 0.f;
    for (int j = s0; j < s1; j++) {
        float w = __expf(ew[j] - mx);
        ew[j] = w;
        s += w;
    }
    denom[n] = s;
}

__global__ __launch_bounds__(256) void gather_k(const int* __restrict__ offs,
                                                const int* __restrict__ ssrc,
                                                const float* __restrict__ ew,
                                                const float* __restrict__ denom,
                                                const float* __restrict__ h,
                                                float* __restrict__ out, int N) {
    int n = blockIdx.x * 4 + (threadIdx.x >> 6);
    int f = threadIdx.x & 63;
    if (n >= N) return;
    int s0 = offs[n], s1 = offs[n + 1];
    float acc = 0.f;
    for (int j = s0; j < s1; j++) {
        acc += h[(size_t)ssrc[j] * 64 + f] * ew[j];
    }
    float invd = 1.0f / (denom[n] + 1e-16f);
    out[(size_t)n * 64 + f] = fmaxf(acc * invd, 0.f);
}

// ---------------- pooling + critic MLP ----------------
__global__ void pool_k(const int* __restrict__ batch, const float* __restrict__ act,
                       float* __restrict__ gp, int N) {
    int g = blockIdx.x;
    int f = threadIdx.x;  // 64 threads
    int lo, hi;
    { int a = 0, b = N; while (a < b) { int m = (a + b) >> 1; if (batch[m] < g) a = m + 1; else b = m; } lo = a; }
    { int a = lo, b = N; while (a < b) { int m = (a + b) >> 1; if (batch[m] < g + 1) a = m + 1; else b = m; } hi = a; }
    float acc = 0.f;
    for (int n = lo; n < hi; n++) acc += act[(size_t)n * 64 + f];
    gp[g * 64 + f] = acc;
}

__global__ __launch_bounds__(128) void mlp_k(const float* __restrict__ gp,
                                             const float* __restrict__ W0,
                                             const float* __restrict__ b0,
                                             const float* __restrict__ W1,
                                             const float* __restrict__ b1,
                                             const float* __restrict__ fW,
                                             const float* __restrict__ fb,
                                             float* __restrict__ out) {
    __shared__ float gv[64];
    __shared__ float t1[128];
    __shared__ float t2[128];
    __shared__ float part[2];
    int g = blockIdx.x;
    int t = threadIdx.x;  // 128 threads (ENC)
    if (t < 64) gv[t] = gp[g * 64 + t];
    __syncthreads();
    float acc = b0[t];
    for (int k = 0; k < 64; k++) acc += gv[k] * W0[k * 128 + t];
    t1[t] = fmaxf(acc, 0.f);
    __syncthreads();
    acc = b1[t];
    for (int k = 0; k < 128; k++) acc += t1[k] * W1[k * 128 + t];
    t2[t] = fmaxf(acc, 0.f);
    __syncthreads();
    float v = t2[t] * fW[t];
    for (int o = 32; o > 0; o >>= 1) v += __shfl_xor(v, o, 64);
    if ((t & 63) == 0) part[t >> 6] = v;
    __syncthreads();
    if (t == 0) out[g] = part[0] + part[1] + fb[0];
}

extern "C" void kernel_launch(void* const* d_in, const int* in_sizes, int n_in,
                              void* d_out, int out_size, void* d_ws, size_t ws_size,
                              hipStream_t stream) {
    const float* x    = (const float*)d_in[0];
    const int*   src  = (const int*)d_in[1];
    const int*   dst  = (const int*)d_in[2];
    const int*   et   = (const int*)d_in[3];
    const int*   batch= (const int*)d_in[4];
    const float* W0   = (const float*)d_in[6];
    const float* W1   = (const float*)d_in[7];
    const float* W2   = (const float*)d_in[8];
    const float* a_src= (const float*)d_in[9];
    const float* a_dst= (const float*)d_in[10];
    const float* etb  = (const float*)d_in[11];
    const float* eW0  = (const float*)d_in[12];
    const float* eb0  = (const float*)d_in[13];
    const float* eW1  = (const float*)d_in[14];
    const float* eb1  = (const float*)d_in[15];
    const float* fW   = (const float*)d_in[16];
    const float* fb   = (const float*)d_in[17];
    float* out = (float*)d_out;

    const int H = in_sizes[9] / 3;       // 64
    const int F = in_sizes[6] / H;       // 128
    const int N = in_sizes[0] / F;       // 50000
    const int E = in_sizes[1];           // 800000
    const int T = in_sizes[11] / 3;      // 3
    const int G = out_size;              // 512

    // ---- workspace layout (fp32/int32 elements) ----
    float* hA    = (float*)d_ws;            // N*64  (transformed h)
    float* hB    = hA + (size_t)N * 64;     // N*64  (layer activations, ping-pong with x input)
    float* ls    = hB + (size_t)N * 64;     // N
    float* ld_   = ls + N;                  // N
    float* denom = ld_ + N;                 // N
    float* ew    = denom + N;               // E
    int*   deg   = (int*)(ew + E);          // N
    int*   offs  = deg + N;                 // N+1
    int*   cursor= offs + N + 1;            // N
    int*   ssrc  = cursor + N;              // E
    int*   setp  = ssrc + E;                // E
    int*   bsum  = setp + E;                // NB

    const int NB = (N + SCAN_B - 1) / SCAN_B;

    hipMemsetAsync(deg, 0, (size_t)N * sizeof(int), stream);
    hipMemsetAsync(cursor, 0, (size_t)N * sizeof(int), stream);

    // CSR build
    deg_k<<<(E + 255) / 256, 256, 0, stream>>>(dst, deg, E);
    scan1_k<<<NB, SCAN_B, 0, stream>>>(deg, offs, bsum, N);
    scan2_k<<<1, 1, 0, stream>>>(bsum, offs, NB, N);
    scan3_k<<<NB, SCAN_B, 0, stream>>>(offs, bsum, N);
    scatter_k<<<(E + 255) / 256, 256, 0, stream>>>(src, dst, et, offs, cursor, ssrc, setp, E);

    const int NB4 = (N + 3) / 4;
    const int NBn = (N + 255) / 256;

    // ---- layer 0: in = x (F=128) ----
    gemm_k<128><<<NB4, 256, 0, stream>>>(x, W0, hA, N);
    logits_k<<<NB4, 256, 0, stream>>>(hA, a_src + 0 * H, a_dst + 0 * H, ls, ld_, N);
    softmax_k<<<NBn, 256, 0, stream>>>(offs, ssrc, setp, ls, ld_, etb + 0 * T, ew, denom, N);
    gather_k<<<NB4, 256, 0, stream>>>(offs, ssrc, ew, denom, hA, hB, N);

    // ---- layer 1: in = hB ----
    gemm_k<64><<<NB4, 256, 0, stream>>>(hB, W1, hA, N);
    logits_k<<<NB4, 256, 0, stream>>>(hA, a_src + 1 * H, a_dst + 1 * H, ls, ld_, N);
    softmax_k<<<NBn, 256, 0, stream>>>(offs, ssrc, setp, ls, ld_, etb + 1 * T, ew, denom, N);
    gather_k<<<NB4, 256, 0, stream>>>(offs, ssrc, ew, denom, hA, hB, N);

    // ---- layer 2: in = hB ----
    gemm_k<64><<<NB4, 256, 0, stream>>>(hB, W2, hA, N);
    logits_k<<<NB4, 256, 0, stream>>>(hA, a_src + 2 * H, a_dst + 2 * H, ls, ld_, N);
    softmax_k<<<NBn, 256, 0, stream>>>(offs, ssrc, setp, ls, ld_, etb + 2 * T, ew, denom, N);
    gather_k<<<NB4, 256, 0, stream>>>(offs, ssrc, ew, denom, hA, hB, N);

    // ---- pool (batch is sorted -> contiguous ranges per graph) + MLP ----
    float* gp = ew;  // reuse edge-weight buffer (G*64 << E)
    pool_k<<<G, 64, 0, stream>>>(batch, hB, gp, N);
    mlp_k<<<G, 128, 0, stream>>>(gp, eW0, eb0, eW1, eb1, fW, fb, out);
}

// Round 2
// 505.537 us; speedup vs baseline: 1.2211x; 1.2211x over previous
//
#include <hip/hip_runtime.h>
#include <hip/hip_bf16.h>
#include <float.h>

#define LEAKY 0.2f
#define SCAN_B 512

// ---------------- CSR build ----------------
__global__ void deg_k(const int* __restrict__ dst, int* __restrict__ deg, int E) {
    int e = blockIdx.x * blockDim.x + threadIdx.x;
    if (e < E) atomicAdd(&deg[dst[e]], 1);
}

__global__ void scan1_k(const int* __restrict__ deg, int* __restrict__ offs,
                        int* __restrict__ bsum, int N) {
    __shared__ int s[SCAN_B];
    int i = blockIdx.x * SCAN_B + threadIdx.x;
    int v = (i < N) ? deg[i] : 0;
    s[threadIdx.x] = v;
    __syncthreads();
    for (int off = 1; off < SCAN_B; off <<= 1) {
        int t = (threadIdx.x >= off) ? s[threadIdx.x - off] : 0;
        __syncthreads();
        s[threadIdx.x] += t;
        __syncthreads();
    }
    if (i < N) offs[i] = s[threadIdx.x] - v;   // exclusive
    if (threadIdx.x == SCAN_B - 1) bsum[blockIdx.x] = s[threadIdx.x];
}

__global__ void scan2_k(int* __restrict__ bsum, int* __restrict__ offs, int NB, int N) {
    if (blockIdx.x == 0 && threadIdx.x == 0) {
        int run = 0;
        for (int b = 0; b < NB; b++) { int t = bsum[b]; bsum[b] = run; run += t; }
        offs[N] = run;
    }
}

__global__ void scan3_k(int* __restrict__ offs, const int* __restrict__ bsum, int N) {
    int i = blockIdx.x * blockDim.x + threadIdx.x;
    if (i < N) offs[i] += bsum[i / SCAN_B];
}

__global__ void scatter_k(const int* __restrict__ src, const int* __restrict__ dst,
                          const int* __restrict__ et, const int* __restrict__ offs,
                          int* __restrict__ cursor, int* __restrict__ ssrc,
                          int* __restrict__ setp, int E) {
    int e = blockIdx.x * blockDim.x + threadIdx.x;
    if (e < E) {
        int d = dst[e];
        int pos = atomicAdd(&cursor[d], 1);
        int j = offs[d] + pos;
        ssrc[j] = src[e];
        setp[j] = et[e];
    }
}

// ---------------- fused GEMM + logits (H = 64 baked in) ----------------
// 64x64 output tile per 256-thread block, 4x4 microtile per thread.
// Epilogue computes ls = h.a_s, ld = h.a_d via 16-lane shuffle reduce.
template <int FIN>
__global__ __launch_bounds__(256) void gemm_fused_k(const float* __restrict__ in,
                                                    const float* __restrict__ W,
                                                    const float* __restrict__ a_s,
                                                    const float* __restrict__ a_d,
                                                    float* __restrict__ h,
                                                    float* __restrict__ ls,
                                                    float* __restrict__ ld_, int N) {
    __shared__ float in_s[64][FIN + 4];   // +4 pad: keeps float4 alignment, 2-way banks (free)
    __shared__ float Wl[FIN][64];

    const int rbase = blockIdx.x * 64;
    const int NV4 = FIN / 4;

    // stage W (FIN*64 floats) via float4
    for (int t = threadIdx.x; t < FIN * 16; t += 256) {
        float4 v = *(const float4*)(W + (size_t)t * 4);
        *(float4*)((float*)Wl + (size_t)t * 4) = v;
    }
    // stage input tile (64 rows x FIN) via float4, coalesced
    for (int t = threadIdx.x; t < 64 * NV4; t += 256) {
        int r = t / NV4, k4 = t % NV4;
        int gr = rbase + r;
        if (gr >= N) gr = N - 1;   // clamp; stores are guarded
        float4 v = *(const float4*)(in + (size_t)gr * FIN + k4 * 4);
        *(float4*)&in_s[r][k4 * 4] = v;
    }
    __syncthreads();

    const int ty = threadIdx.x >> 4;   // 0..15 -> row group (4 rows)
    const int tx = threadIdx.x & 15;   // 0..15 -> col group (4 cols)

    float acc[4][4] = {};
#pragma unroll 4
    for (int k = 0; k < FIN; ++k) {
        float4 wv = *(const float4*)&Wl[k][tx * 4];
        float a0 = in_s[ty * 4 + 0][k];
        float a1 = in_s[ty * 4 + 1][k];
        float a2 = in_s[ty * 4 + 2][k];
        float a3 = in_s[ty * 4 + 3][k];
        acc[0][0] += a0 * wv.x; acc[0][1] += a0 * wv.y; acc[0][2] += a0 * wv.z; acc[0][3] += a0 * wv.w;
        acc[1][0] += a1 * wv.x; acc[1][1] += a1 * wv.y; acc[1][2] += a1 * wv.z; acc[1][3] += a1 * wv.w;
        acc[2][0] += a2 * wv.x; acc[2][1] += a2 * wv.y; acc[2][2] += a2 * wv.z; acc[2][3] += a2 * wv.w;
        acc[3][0] += a3 * wv.x; acc[3][1] += a3 * wv.y; acc[3][2] += a3 * wv.z; acc[3][3] += a3 * wv.w;
    }

    float4 asv = *(const float4*)(a_s + tx * 4);
    float4 adv = *(const float4*)(a_d + tx * 4);
#pragma unroll
    for (int i = 0; i < 4; ++i) {
        int row = rbase + ty * 4 + i;
        float lsv = acc[i][0] * asv.x + acc[i][1] * asv.y + acc[i][2] * asv.z + acc[i][3] * asv.w;
        float ldv = acc[i][0] * adv.x + acc[i][1] * adv.y + acc[i][2] * adv.z + acc[i][3] * adv.w;
        // reduce across the 16 tx lanes (lane bits 0..3)
        for (int o = 1; o < 16; o <<= 1) {
            lsv += __shfl_xor(lsv, o, 64);
            ldv += __shfl_xor(ldv, o, 64);
        }
        if (row < N) {
            float4 hv = make_float4(acc[i][0], acc[i][1], acc[i][2], acc[i][3]);
            *(float4*)&h[(size_t)row * 64 + tx * 4] = hv;
            if (tx == 0) { ls[row] = lsv; ld_[row] = ldv; }
        }
    }
}

// ---------------- edge softmax ----------------
__global__ __launch_bounds__(256) void softmax_k(const int* __restrict__ offs,
                                                 const int* __restrict__ ssrc,
                                                 const int* __restrict__ setp,
                                                 const float* __restrict__ ls,
                                                 const float* __restrict__ ld_,
                                                 const float* __restrict__ etb,
                                                 float* __restrict__ ew,
                                                 float* __restrict__ denom, int N) {
    int n = blockIdx.x * blockDim.x + threadIdx.x;
    if (n >= N) return;
    int s0 = offs[n], s1 = offs[n + 1];
    float myld = ld_[n];
    float mx = -FLT_MAX;
    for (int j = s0; j < s1; j++) {
        float ev = ls[ssrc[j]] + myld + etb[setp[j]];
        ev = ev > 0.f ? ev : LEAKY * ev;
        ew[j] = ev;
        mx = fmaxf(mx, ev);
    }
    float s = 0.f;
    for (int j = s0; j < s1; j++) {
        float w = __expf(ew[j] - mx);
        ew[j] = w;
        s += w;
    }
    denom[n] = s;
}

__global__ __launch_bounds__(256) void gather_k(const int* __restrict__ offs,
                                                const int* __restrict__ ssrc,
                                                const float* __restrict__ ew,
                                                const float* __restrict__ denom,
                                                const float* __restrict__ h,
                                                float* __restrict__ out, int N) {
    int n = blockIdx.x * 4 + (threadIdx.x >> 6);
    int f = threadIdx.x & 63;
    if (n >= N) return;
    int s0 = offs[n], s1 = offs[n + 1];
    float acc = 0.f;
    for (int j = s0; j < s1; j++) {
        acc += h[(size_t)ssrc[j] * 64 + f] * ew[j];
    }
    float invd = 1.0f / (denom[n] + 1e-16f);
    out[(size_t)n * 64 + f] = fmaxf(acc * invd, 0.f);
}

// ---------------- pooling + critic MLP ----------------
__global__ void pool_k(const int* __restrict__ batch, const float* __restrict__ act,
                       float* __restrict__ gp, int N) {
    int g = blockIdx.x;
    int f = threadIdx.x;  // 64 threads
    int lo, hi;
    { int a = 0, b = N; while (a < b) { int m = (a + b) >> 1; if (batch[m] < g) a = m + 1; else b = m; } lo = a; }
    { int a = lo, b = N; while (a < b) { int m = (a + b) >> 1; if (batch[m] < g + 1) a = m + 1; else b = m; } hi = a; }
    float acc = 0.f;
    for (int n = lo; n < hi; n++) acc += act[(size_t)n * 64 + f];
    gp[g * 64 + f] = acc;
}

__global__ __launch_bounds__(128) void mlp_k(const float* __restrict__ gp,
                                             const float* __restrict__ W0,
                                             const float* __restrict__ b0,
                                             const float* __restrict__ W1,
                                             const float* __restrict__ b1,
                                             const float* __restrict__ fW,
                                             const float* __restrict__ fb,
                                             float* __restrict__ out) {
    __shared__ float gv[64];
    __shared__ float t1[128];
    __shared__ float t2[128];
    __shared__ float part[2];
    int g = blockIdx.x;
    int t = threadIdx.x;  // 128 threads (ENC)
    if (t < 64) gv[t] = gp[g * 64 + t];
    __syncthreads();
    float acc = b0[t];
    for (int k = 0; k < 64; k++) acc += gv[k] * W0[k * 128 + t];
    t1[t] = fmaxf(acc, 0.f);
    __syncthreads();
    acc = b1[t];
    for (int k = 0; k < 128; k++) acc += t1[k] * W1[k * 128 + t];
    t2[t] = fmaxf(acc, 0.f);
    __syncthreads();
    float v = t2[t] * fW[t];
    for (int o = 32; o > 0; o >>= 1) v += __shfl_xor(v, o, 64);
    if ((t & 63) == 0) part[t >> 6] = v;
    __syncthreads();
    if (t == 0) out[g] = part[0] + part[1] + fb[0];
}

extern "C" void kernel_launch(void* const* d_in, const int* in_sizes, int n_in,
                              void* d_out, int out_size, void* d_ws, size_t ws_size,
                              hipStream_t stream) {
    const float* x    = (const float*)d_in[0];
    const int*   src  = (const int*)d_in[1];
    const int*   dst  = (const int*)d_in[2];
    const int*   et   = (const int*)d_in[3];
    const int*   batch= (const int*)d_in[4];
    const float* W0   = (const float*)d_in[6];
    const float* W1   = (const float*)d_in[7];
    const float* W2   = (const float*)d_in[8];
    const float* a_src= (const float*)d_in[9];
    const float* a_dst= (const float*)d_in[10];
    const float* etb  = (const float*)d_in[11];
    const float* eW0  = (const float*)d_in[12];
    const float* eb0  = (const float*)d_in[13];
    const float* eW1  = (const float*)d_in[14];
    const float* eb1  = (const float*)d_in[15];
    const float* fW   = (const float*)d_in[16];
    const float* fb   = (const float*)d_in[17];
    float* out = (float*)d_out;

    const int H = in_sizes[9] / 3;       // 64
    const int F = in_sizes[6] / H;       // 128
    const int N = in_sizes[0] / F;       // 50000
    const int E = in_sizes[1];           // 800000
    const int T = in_sizes[11] / 3;      // 3
    const int G = out_size;              // 512

    // ---- workspace layout (fp32/int32 elements) ----
    float* hA    = (float*)d_ws;            // N*64  (transformed h)
    float* hB    = hA + (size_t)N * 64;     // N*64  (layer activations)
    float* ls    = hB + (size_t)N * 64;     // N
    float* ld_   = ls + N;                  // N
    float* denom = ld_ + N;                 // N
    float* ew    = denom + N;               // E
    int*   deg   = (int*)(ew + E);          // N
    int*   offs  = deg + N;                 // N+1
    int*   cursor= offs + N + 1;            // N
    int*   ssrc  = cursor + N;              // E
    int*   setp  = ssrc + E;                // E
    int*   bsum  = setp + E;                // NB

    const int NB = (N + SCAN_B - 1) / SCAN_B;

    hipMemsetAsync(deg, 0, (size_t)N * sizeof(int), stream);
    hipMemsetAsync(cursor, 0, (size_t)N * sizeof(int), stream);

    // CSR build
    deg_k<<<(E + 255) / 256, 256, 0, stream>>>(dst, deg, E);
    scan1_k<<<NB, SCAN_B, 0, stream>>>(deg, offs, bsum, N);
    scan2_k<<<1, 1, 0, stream>>>(bsum, offs, NB, N);
    scan3_k<<<NB, SCAN_B, 0, stream>>>(offs, bsum, N);
    scatter_k<<<(E + 255) / 256, 256, 0, stream>>>(src, dst, et, offs, cursor, ssrc, setp, E);

    const int NB64 = (N + 63) / 64;
    const int NB4  = (N + 3) / 4;
    const int NBn  = (N + 255) / 256;

    // ---- layer 0: in = x (F=128) ----
    gemm_fused_k<128><<<NB64, 256, 0, stream>>>(x, W0, a_src + 0 * H, a_dst + 0 * H, hA, ls, ld_, N);
    softmax_k<<<NBn, 256, 0, stream>>>(offs, ssrc, setp, ls, ld_, etb + 0 * T, ew, denom, N);
    gather_k<<<NB4, 256, 0, stream>>>(offs, ssrc, ew, denom, hA, hB, N);

    // ---- layer 1: in = hB ----
    gemm_fused_k<64><<<NB64, 256, 0, stream>>>(hB, W1, a_src + 1 * H, a_dst + 1 * H, hA, ls, ld_, N);
    softmax_k<<<NBn, 256, 0, stream>>>(offs, ssrc, setp, ls, ld_, etb + 1 * T, ew, denom, N);
    gather_k<<<NB4, 256, 0, stream>>>(offs, ssrc, ew, denom, hA, hB, N);

    // ---- layer 2: in = hB ----
    gemm_fused_k<64><<<NB64, 256, 0, stream>>>(hB, W2, a_src + 2 * H, a_dst + 2 * H, hA, ls, ld_, N);
    softmax_k<<<NBn, 256, 0, stream>>>(offs, ssrc, setp, ls, ld_, etb + 2 * T, ew, denom, N);
    gather_k<<<NB4, 256, 0, stream>>>(offs, ssrc, ew, denom, hA, hB, N);

    // ---- pool (batch sorted -> contiguous ranges) + MLP ----
    float* gp = ew;  // reuse edge buffer (G*64 << E)
    pool_k<<<G, 64, 0, stream>>>(batch, hB, gp, N);
    mlp_k<<<G, 128, 0, stream>>>(gp, eW0, eb0, eW1, eb1, fW, fb, out);
}

// Round 3
// 297.512 us; speedup vs baseline: 2.0750x; 1.6992x over previous
//
#include <hip/hip_runtime.h>
#include <hip/hip_bf16.h>
#include <float.h>

#define LEAKY 0.2f
#define SCAN_B 512

// ---------------- CSR build ----------------
__global__ void deg_k(const int* __restrict__ dst, int* __restrict__ deg, int E) {
    int e = blockIdx.x * blockDim.x + threadIdx.x;
    if (e < E) atomicAdd(&deg[dst[e]], 1);
}

__global__ void scan1_k(const int* __restrict__ deg, int* __restrict__ offs,
                        int* __restrict__ bsum, int N) {
    __shared__ int s[SCAN_B];
    int i = blockIdx.x * SCAN_B + threadIdx.x;
    int v = (i < N) ? deg[i] : 0;
    s[threadIdx.x] = v;
    __syncthreads();
    for (int off = 1; off < SCAN_B; off <<= 1) {
        int t = (threadIdx.x >= off) ? s[threadIdx.x - off] : 0;
        __syncthreads();
        s[threadIdx.x] += t;
        __syncthreads();
    }
    if (i < N) offs[i] = s[threadIdx.x] - v;   // exclusive
    if (threadIdx.x == SCAN_B - 1) bsum[blockIdx.x] = s[threadIdx.x];
}

__global__ void scan2_k(int* __restrict__ bsum, int* __restrict__ offs, int NB, int N) {
    if (blockIdx.x == 0 && threadIdx.x == 0) {
        int run = 0;
        for (int b = 0; b < NB; b++) { int t = bsum[b]; bsum[b] = run; run += t; }
        offs[N] = run;
    }
}

__global__ void scan3_k(int* __restrict__ offs, const int* __restrict__ bsum, int N) {
    int i = blockIdx.x * blockDim.x + threadIdx.x;
    if (i < N) offs[i] += bsum[i / SCAN_B];
}

__global__ void scatter_k(const int* __restrict__ src, const int* __restrict__ dst,
                          const int* __restrict__ et, const int* __restrict__ offs,
                          int* __restrict__ cursor, int* __restrict__ ssrc,
                          int* __restrict__ setp, int E) {
    int e = blockIdx.x * blockDim.x + threadIdx.x;
    if (e < E) {
        int d = dst[e];
        int pos = atomicAdd(&cursor[d], 1);
        int j = offs[d] + pos;
        ssrc[j] = src[e];
        setp[j] = et[e];
    }
}

// ---------------- fused GEMM + logits (H = 64 baked in) ----------------
template <int FIN>
__global__ __launch_bounds__(256) void gemm_fused_k(const float* __restrict__ in,
                                                    const float* __restrict__ W,
                                                    const float* __restrict__ a_s,
                                                    const float* __restrict__ a_d,
                                                    float* __restrict__ h,
                                                    float* __restrict__ ls,
                                                    float* __restrict__ ld_, int N) {
    __shared__ float in_s[64][FIN + 4];
    __shared__ float Wl[FIN][64];

    const int rbase = blockIdx.x * 64;
    const int NV4 = FIN / 4;

    for (int t = threadIdx.x; t < FIN * 16; t += 256) {
        float4 v = *(const float4*)(W + (size_t)t * 4);
        *(float4*)((float*)Wl + (size_t)t * 4) = v;
    }
    for (int t = threadIdx.x; t < 64 * NV4; t += 256) {
        int r = t / NV4, k4 = t % NV4;
        int gr = rbase + r;
        if (gr >= N) gr = N - 1;
        float4 v = *(const float4*)(in + (size_t)gr * FIN + k4 * 4);
        *(float4*)&in_s[r][k4 * 4] = v;
    }
    __syncthreads();

    const int ty = threadIdx.x >> 4;
    const int tx = threadIdx.x & 15;

    float acc[4][4] = {};
#pragma unroll 4
    for (int k = 0; k < FIN; ++k) {
        float4 wv = *(const float4*)&Wl[k][tx * 4];
        float a0 = in_s[ty * 4 + 0][k];
        float a1 = in_s[ty * 4 + 1][k];
        float a2 = in_s[ty * 4 + 2][k];
        float a3 = in_s[ty * 4 + 3][k];
        acc[0][0] += a0 * wv.x; acc[0][1] += a0 * wv.y; acc[0][2] += a0 * wv.z; acc[0][3] += a0 * wv.w;
        acc[1][0] += a1 * wv.x; acc[1][1] += a1 * wv.y; acc[1][2] += a1 * wv.z; acc[1][3] += a1 * wv.w;
        acc[2][0] += a2 * wv.x; acc[2][1] += a2 * wv.y; acc[2][2] += a2 * wv.z; acc[2][3] += a2 * wv.w;
        acc[3][0] += a3 * wv.x; acc[3][1] += a3 * wv.y; acc[3][2] += a3 * wv.z; acc[3][3] += a3 * wv.w;
    }

    float4 asv = *(const float4*)(a_s + tx * 4);
    float4 adv = *(const float4*)(a_d + tx * 4);
#pragma unroll
    for (int i = 0; i < 4; ++i) {
        int row = rbase + ty * 4 + i;
        float lsv = acc[i][0] * asv.x + acc[i][1] * asv.y + acc[i][2] * asv.z + acc[i][3] * asv.w;
        float ldv = acc[i][0] * adv.x + acc[i][1] * adv.y + acc[i][2] * adv.z + acc[i][3] * adv.w;
        for (int o = 1; o < 16; o <<= 1) {
            lsv += __shfl_xor(lsv, o, 64);
            ldv += __shfl_xor(ldv, o, 64);
        }
        if (row < N) {
            float4 hv = make_float4(acc[i][0], acc[i][1], acc[i][2], acc[i][3]);
            *(float4*)&h[(size_t)row * 64 + tx * 4] = hv;
            if (tx == 0) { ls[row] = lsv; ld_[row] = ldv; }
        }
    }
}

// ---------------- edge softmax: one node per 16-lane group ----------------
__global__ __launch_bounds__(256) void softmax_k(const int* __restrict__ offs,
                                                 const int* __restrict__ ssrc,
                                                 const int* __restrict__ setp,
                                                 const float* __restrict__ ls,
                                                 const float* __restrict__ ld_,
                                                 const float* __restrict__ etb,
                                                 float* __restrict__ ew,
                                                 float* __restrict__ denom, int N) {
    int grp = threadIdx.x >> 4;
    int l = threadIdx.x & 15;
    int n = blockIdx.x * 16 + grp;
    if (n >= N) return;
    int s0 = offs[n], s1 = offs[n + 1];
    float myld = ld_[n];
    float mx = -FLT_MAX;
    for (int j = s0 + l; j < s1; j += 16) {
        float ev = ls[ssrc[j]] + myld + etb[setp[j]];
        ev = ev > 0.f ? ev : LEAKY * ev;
        ew[j] = ev;
        mx = fmaxf(mx, ev);
    }
#pragma unroll
    for (int o = 1; o < 16; o <<= 1) mx = fmaxf(mx, __shfl_xor(mx, o, 64));
    float s = 0.f;
    for (int j = s0 + l; j < s1; j += 16) {
        float w = __expf(ew[j] - mx);
        ew[j] = w;
        s += w;
    }
#pragma unroll
    for (int o = 1; o < 16; o <<= 1) s += __shfl_xor(s, o, 64);
    if (l == 0) denom[n] = s;
}

// ---------------- weighted gather: 16 lanes x float4 per node, unroll 4 ----------------
__global__ __launch_bounds__(256) void gather_k(const int* __restrict__ offs,
                                                const int* __restrict__ ssrc,
                                                const float* __restrict__ ew,
                                                const float* __restrict__ denom,
                                                const float* __restrict__ h,
                                                float* __restrict__ out, int N) {
    int grp = threadIdx.x >> 4;
    int l = threadIdx.x & 15;
    int n = blockIdx.x * 16 + grp;
    if (n >= N) return;
    int s0 = offs[n], s1 = offs[n + 1];
    const float4* h4 = (const float4*)h;
    float ax = 0.f, ay = 0.f, az = 0.f, aw = 0.f;
    int j = s0;
    for (; j + 3 < s1; j += 4) {
        int i0 = ssrc[j], i1 = ssrc[j + 1], i2 = ssrc[j + 2], i3 = ssrc[j + 3];
        float w0 = ew[j], w1 = ew[j + 1], w2 = ew[j + 2], w3 = ew[j + 3];
        float4 v0 = h4[(size_t)i0 * 16 + l];
        float4 v1 = h4[(size_t)i1 * 16 + l];
        float4 v2 = h4[(size_t)i2 * 16 + l];
        float4 v3 = h4[(size_t)i3 * 16 + l];
        ax += v0.x * w0 + v1.x * w1 + v2.x * w2 + v3.x * w3;
        ay += v0.y * w0 + v1.y * w1 + v2.y * w2 + v3.y * w3;
        az += v0.z * w0 + v1.z * w1 + v2.z * w2 + v3.z * w3;
        aw += v0.w * w0 + v1.w * w1 + v2.w * w2 + v3.w * w3;
    }
    for (; j < s1; j++) {
        int i0 = ssrc[j];
        float w0 = ew[j];
        float4 v0 = h4[(size_t)i0 * 16 + l];
        ax += v0.x * w0; ay += v0.y * w0; az += v0.z * w0; aw += v0.w * w0;
    }
    float invd = 1.0f / (denom[n] + 1e-16f);
    float4 r;
    r.x = fmaxf(ax * invd, 0.f);
    r.y = fmaxf(ay * invd, 0.f);
    r.z = fmaxf(az * invd, 0.f);
    r.w = fmaxf(aw * invd, 0.f);
    ((float4*)out)[(size_t)n * 16 + l] = r;
}

// ---------------- pooling + critic MLP ----------------
__global__ __launch_bounds__(256) void pool_k(const int* __restrict__ batch,
                                              const float* __restrict__ act,
                                              float* __restrict__ gp, int N) {
    __shared__ float s[256];
    int g = blockIdx.x;
    int f = threadIdx.x & 63;
    int rc = threadIdx.x >> 6;   // 0..3 row chunk
    int lo, hi;
    { int a = 0, b = N; while (a < b) { int m = (a + b) >> 1; if (batch[m] < g) a = m + 1; else b = m; } lo = a; }
    { int a = lo, b = N; while (a < b) { int m = (a + b) >> 1; if (batch[m] < g + 1) a = m + 1; else b = m; } hi = a; }
    float acc = 0.f;
    for (int n = lo + rc; n < hi; n += 4) acc += act[(size_t)n * 64 + f];
    s[threadIdx.x] = acc;
    __syncthreads();
    if (threadIdx.x < 64)
        gp[g * 64 + threadIdx.x] = s[threadIdx.x] + s[threadIdx.x + 64] + s[threadIdx.x + 128] + s[threadIdx.x + 192];
}

__global__ __launch_bounds__(128) void mlp_k(const float* __restrict__ gp,
                                             const float* __restrict__ W0,
                                             const float* __restrict__ b0,
                                             const float* __restrict__ W1,
                                             const float* __restrict__ b1,
                                             const float* __restrict__ fW,
                                             const float* __restrict__ fb,
                                             float* __restrict__ out) {
    __shared__ float gv[64];
    __shared__ float t1[128];
    __shared__ float t2[128];
    __shared__ float part[2];
    int g = blockIdx.x;
    int t = threadIdx.x;
    if (t < 64) gv[t] = gp[g * 64 + t];
    __syncthreads();
    float acc = b0[t];
    for (int k = 0; k < 64; k++) acc += gv[k] * W0[k * 128 + t];
    t1[t] = fmaxf(acc, 0.f);
    __syncthreads();
    acc = b1[t];
    for (int k = 0; k < 128; k++) acc += t1[k] * W1[k * 128 + t];
    t2[t] = fmaxf(acc, 0.f);
    __syncthreads();
    float v = t2[t] * fW[t];
    for (int o = 32; o > 0; o >>= 1) v += __shfl_xor(v, o, 64);
    if ((t & 63) == 0) part[t >> 6] = v;
    __syncthreads();
    if (t == 0) out[g] = part[0] + part[1] + fb[0];
}

extern "C" void kernel_launch(void* const* d_in, const int* in_sizes, int n_in,
                              void* d_out, int out_size, void* d_ws, size_t ws_size,
                              hipStream_t stream) {
    const float* x    = (const float*)d_in[0];
    const int*   src  = (const int*)d_in[1];
    const int*   dst  = (const int*)d_in[2];
    const int*   et   = (const int*)d_in[3];
    const int*   batch= (const int*)d_in[4];
    const float* W0   = (const float*)d_in[6];
    const float* W1   = (const float*)d_in[7];
    const float* W2   = (const float*)d_in[8];
    const float* a_src= (const float*)d_in[9];
    const float* a_dst= (const float*)d_in[10];
    const float* etb  = (const float*)d_in[11];
    const float* eW0  = (const float*)d_in[12];
    const float* eb0  = (const float*)d_in[13];
    const float* eW1  = (const float*)d_in[14];
    const float* eb1  = (const float*)d_in[15];
    const float* fW   = (const float*)d_in[16];
    const float* fb   = (const float*)d_in[17];
    float* out = (float*)d_out;

    const int H = in_sizes[9] / 3;       // 64
    const int F = in_sizes[6] / H;       // 128
    const int N = in_sizes[0] / F;       // 50000
    const int E = in_sizes[1];           // 800000
    const int T = in_sizes[11] / 3;      // 3
    const int G = out_size;              // 512

    float* hA    = (float*)d_ws;
    float* hB    = hA + (size_t)N * 64;
    float* ls    = hB + (size_t)N * 64;
    float* ld_   = ls + N;
    float* denom = ld_ + N;
    float* ew    = denom + N;
    int*   deg   = (int*)(ew + E);
    int*   offs  = deg + N;
    int*   cursor= offs + N + 1;
    int*   ssrc  = cursor + N;
    int*   setp  = ssrc + E;
    int*   bsum  = setp + E;

    const int NB = (N + SCAN_B - 1) / SCAN_B;

    hipMemsetAsync(deg, 0, (size_t)N * sizeof(int), stream);
    hipMemsetAsync(cursor, 0, (size_t)N * sizeof(int), stream);

    deg_k<<<(E + 255) / 256, 256, 0, stream>>>(dst, deg, E);
    scan1_k<<<NB, SCAN_B, 0, stream>>>(deg, offs, bsum, N);
    scan2_k<<<1, 1, 0, stream>>>(bsum, offs, NB, N);
    scan3_k<<<NB, SCAN_B, 0, stream>>>(offs, bsum, N);
    scatter_k<<<(E + 255) / 256, 256, 0, stream>>>(src, dst, et, offs, cursor, ssrc, setp, E);

    const int NB64 = (N + 63) / 64;
    const int NB16 = (N + 15) / 16;

    // ---- layer 0 ----
    gemm_fused_k<128><<<NB64, 256, 0, stream>>>(x, W0, a_src + 0 * H, a_dst + 0 * H, hA, ls, ld_, N);
    softmax_k<<<NB16, 256, 0, stream>>>(offs, ssrc, setp, ls, ld_, etb + 0 * T, ew, denom, N);
    gather_k<<<NB16, 256, 0, stream>>>(offs, ssrc, ew, denom, hA, hB, N);

    // ---- layer 1 ----
    gemm_fused_k<64><<<NB64, 256, 0, stream>>>(hB, W1, a_src + 1 * H, a_dst + 1 * H, hA, ls, ld_, N);
    softmax_k<<<NB16, 256, 0, stream>>>(offs, ssrc, setp, ls, ld_, etb + 1 * T, ew, denom, N);
    gather_k<<<NB16, 256, 0, stream>>>(offs, ssrc, ew, denom, hA, hB, N);

    // ---- layer 2 ----
    gemm_fused_k<64><<<NB64, 256, 0, stream>>>(hB, W2, a_src + 2 * H, a_dst + 2 * H, hA, ls, ld_, N);
    softmax_k<<<NB16, 256, 0, stream>>>(offs, ssrc, setp, ls, ld_, etb + 2 * T, ew, denom, N);
    gather_k<<<NB16, 256, 0, stream>>>(offs, ssrc, ew, denom, hA, hB, N);

    // ---- pool + MLP ----
    float* gp = ew;
    pool_k<<<G, 256, 0, stream>>>(batch, hB, gp, N);
    mlp_k<<<G, 128, 0, stream>>>(gp, eW0, eb0, eW1, eb1, fW, fb, out);
}